// Round 5
// baseline (123.926 us; speedup 1.0000x reference)
//
#include <hip/hip_runtime.h>
#include <hip/hip_bf16.h>

typedef __attribute__((ext_vector_type(4))) float f32x4;
typedef __attribute__((ext_vector_type(8))) short bf16x8;

#define HW    16384   // 128*128
#define CDIM  256
#define ABUF  8192    // one A buffer: 128 px * 64 B (32 k bf16)
#define BOFF  16384   // B region start (2 A buffers)

__device__ __forceinline__ unsigned short f2bf(float x) {
    __hip_bfloat16 h = __float2bfloat16(x);
    return *reinterpret_cast<unsigned short*>(&h);
}
__device__ __forceinline__ float bf2f(unsigned short u) {
    union { unsigned u; float f; } c; c.u = ((unsigned)u) << 16;
    return c.f;
}

// F2t[px][c] = sum_k W1[c,k] * feat[k][px]  (bf16, channel-last)
// BM=128 px, BN=64 c (4 n-quarters, XCD-sibling swizzle), BK=32, 8 K-steps.
// A LDS: [128px][32k bf16], byte = px*64 + ((2k) ^ (((px>>2)&3)<<4))
// B LDS: [64c][256k bf16],  byte = c*512 + ((2k) ^ ((c&7)<<4))
// Bank-checked: all fragment reads + B-stage writes free (8 lanes / 4-bank
// group over b128's 4 cycles); A-stage write worst-case 4-way (tiny volume).
// One barrier per K-step (A double-buffered), depth-2 register prefetch.
__global__ __launch_bounds__(256, 3) void f2_gemm(
    const float* __restrict__ feat, const float* __restrict__ W1,
    unsigned short* __restrict__ f2t) {
    __shared__ __attribute__((aligned(16))) char ldsc[49152];

    const int t    = threadIdx.x;
    const int lane = t & 63;
    const int wid  = t >> 6;
    const int kg   = lane >> 4;      // 0..3 (16B k-granule)
    const int rr   = lane & 15;

    // b = xcd + 8*nq + 32*j  ->  m-tile = xcd*128 + j; 4 nq-siblings share XCD
    const int b      = blockIdx.x;
    const int m      = ((b & 7) << 7) | (b >> 5);
    const int nq     = (b >> 3) & 3;
    const int m_base = m << 7;
    const float* fb  = feat + (size_t)(m_base >> 14) * (CDIM * HW) + (m_base & (HW - 1));
    const float* wb  = W1 + (size_t)nq * 64 * CDIM;

    const int q   = t >> 3;          // px-quad 0..31 (sm0 = 4q)
    const int sm0 = q << 2;
    const int kb  = (t & 7) << 2;    // 4 k-rows per thread

    const int wm = wid >> 1;         // px slab of 64
    const int wn = wid & 1;          // c slab of 32

    float av[2][4][4];               // [regbuf][dk][px-in-quad]
    f32x4 acc[4][2] = {};            // [mi(px)][ni(c)] -> D[c][px]

    auto load_a = [&](int kk, int buf) {
        const float* p = fb + (size_t)(kk * 32 + kb) * HW + sm0;
#pragma unroll
        for (int dk = 0; dk < 4; ++dk) {
            const float4 v = *reinterpret_cast<const float4*>(p + (size_t)dk * HW);
            av[buf][dk][0] = v.x; av[buf][dk][1] = v.y;
            av[buf][dk][2] = v.z; av[buf][dk][3] = v.w;
        }
    };
    auto write_a = [&](int buf, int lbuf) {
        char* base = ldsc + lbuf * ABUF;
#pragma unroll
        for (int p = 0; p < 4; ++p) {
            const int px = sm0 + p;
            ushort4 w;
            w.x = f2bf(av[buf][0][p]); w.y = f2bf(av[buf][1][p]);
            w.z = f2bf(av[buf][2][p]); w.w = f2bf(av[buf][3][p]);
            *reinterpret_cast<ushort4*>(
                base + px * 64 + ((kb * 2) ^ (((px >> 2) & 3) << 4))) = w;
        }
    };

    // ---- prologue: A(0), A(1) in flight; stage W1-quarter (64c x 256k) ----
    load_a(0, 0);
    load_a(1, 1);
    {
        const int c  = t >> 2;            // 0..63
        const int sb = t & 3;             // 128B sub-block of the 512B row
        const float* wp = wb + (size_t)c * CDIM + sb * 64;
        char* brow = ldsc + BOFF + c * 512;
#pragma unroll
        for (int j = 0; j < 8; ++j) {
            const float4 u = *reinterpret_cast<const float4*>(wp + j * 8);
            const float4 v = *reinterpret_cast<const float4*>(wp + j * 8 + 4);
            bf16x8 w;
            w[0] = (short)f2bf(u.x); w[1] = (short)f2bf(u.y);
            w[2] = (short)f2bf(u.z); w[3] = (short)f2bf(u.w);
            w[4] = (short)f2bf(v.x); w[5] = (short)f2bf(v.y);
            w[6] = (short)f2bf(v.z); w[7] = (short)f2bf(v.w);
            const int kbyte = sb * 128 + j * 16;           // 2k
            *reinterpret_cast<bf16x8*>(
                brow + (kbyte ^ ((c & 7) << 4))) = w;
        }
    }
    write_a(0, 0);
    __syncthreads();

    // ---- main loop: ONE barrier per K-step; A(kk+2) in flight over compute(kk)
#pragma unroll
    for (int kk = 0; kk < 8; ++kk) {
        if (kk + 2 < 8) load_a(kk + 2, kk & 1);
        {
            bf16x8 wf[2], ff[4];
#pragma unroll
            for (int ni = 0; ni < 2; ++ni) {
                const int c = wn * 32 + ni * 16 + rr;
                wf[ni] = *reinterpret_cast<const bf16x8*>(
                    ldsc + BOFF + c * 512 + ((kk * 64 + kg * 16) ^ ((c & 7) << 4)));
            }
#pragma unroll
            for (int mi = 0; mi < 4; ++mi) {
                const int px = wm * 64 + mi * 16 + rr;
                ff[mi] = *reinterpret_cast<const bf16x8*>(
                    ldsc + (kk & 1) * ABUF + px * 64 +
                    ((kg * 16) ^ (((px >> 2) & 3) << 4)));
            }
#pragma unroll
            for (int mi = 0; mi < 4; ++mi)
#pragma unroll
                for (int ni = 0; ni < 2; ++ni)
                    acc[mi][ni] = __builtin_amdgcn_mfma_f32_16x16x32_bf16(
                        wf[ni], ff[mi], acc[mi][ni], 0, 0, 0);   // D[c][px]
        }
        if (kk + 1 < 8) {
            write_a((kk + 1) & 1, (kk + 1) & 1);
            __syncthreads();
        }
    }

    // ---- epilogue: lane holds 4 consecutive c for fixed px -> 8B stores ----
#pragma unroll
    for (int mi = 0; mi < 4; ++mi) {
        const int px = m_base + wm * 64 + mi * 16 + rr;
#pragma unroll
        for (int ni = 0; ni < 2; ++ni) {
            const int c0 = nq * 64 + wn * 32 + ni * 16 + kg * 4;
            uint2 v;
            v.x = (unsigned)f2bf(acc[mi][ni][0]) | ((unsigned)f2bf(acc[mi][ni][1]) << 16);
            v.y = (unsigned)f2bf(acc[mi][ni][2]) | ((unsigned)f2bf(acc[mi][ni][3]) << 16);
            *reinterpret_cast<uint2*>(f2t + (size_t)px * CDIM + c0) = v;
        }
    }
}

// One wave per sample point: bilinear-weighted sum of 4 contiguous 512B rows
// of F2t, then relu(s+b1) . W2 -> 2 scalars, out = batch_edges + d.
__global__ __launch_bounds__(256) void point_kernel(
    const unsigned short* __restrict__ f2t,
    const float* __restrict__ be,
    const float* __restrict__ b1, const float* __restrict__ W2,
    float* __restrict__ out) {
    const int p    = (blockIdx.x * 256 + threadIdx.x) >> 6;   // 0..65535
    const int lane = threadIdx.x & 63;

    const float ex = be[p * 2 + 0];
    const float ey = be[p * 2 + 1];
    const float gx = ex * (2.0f / 128.0f) - 1.0f;
    const float gy = ey * (2.0f / 128.0f) - 1.0f;
    const float px = (gx + 1.0f) * 64.0f - 0.5f;
    const float py = (gy + 1.0f) * 64.0f - 0.5f;
    const float x0f = floorf(px), y0f = floorf(py);
    const int   x0 = (int)x0f, y0 = (int)y0f;
    const float wx1 = px - x0f, wy1 = py - y0f;
    const float wx0 = 1.0f - wx1, wy0 = 1.0f - wy1;

    const size_t pix_base = (size_t)(p >> 13) * HW;
    const int c0 = lane * 4;

    float s0 = 0.f, s1 = 0.f, s2 = 0.f, s3 = 0.f;
#pragma unroll
    for (int cy = 0; cy < 2; ++cy) {
        const int   yi  = y0 + cy;
        const float wy  = cy ? wy1 : wy0;
        const bool  yin = (yi >= 0) && (yi < 128);
        const int   yc  = min(max(yi, 0), 127);
#pragma unroll
        for (int cx = 0; cx < 2; ++cx) {
            const int   xi  = x0 + cx;
            const float wx  = cx ? wx1 : wx0;
            const bool  xin = (xi >= 0) && (xi < 128);
            const int   xc  = min(max(xi, 0), 127);
            const float w   = wx * wy * (float)(xin && yin);
            const ushort4 v = *reinterpret_cast<const ushort4*>(
                &f2t[(pix_base + (size_t)yc * 128 + xc) * 256 + c0]);
            s0 += w * bf2f(v.x); s1 += w * bf2f(v.y);
            s2 += w * bf2f(v.z); s3 += w * bf2f(v.w);
        }
    }
    const float4 bb  = *reinterpret_cast<const float4*>(&b1[c0]);
    const float4 w2a = *reinterpret_cast<const float4*>(&W2[c0]);
    const float4 w2b = *reinterpret_cast<const float4*>(&W2[256 + c0]);
    const float h0 = fmaxf(s0 + bb.x, 0.f);
    const float h1 = fmaxf(s1 + bb.y, 0.f);
    const float h2 = fmaxf(s2 + bb.z, 0.f);
    const float h3 = fmaxf(s3 + bb.w, 0.f);
    float a0 = h0 * w2a.x + h1 * w2a.y + h2 * w2a.z + h3 * w2a.w;
    float a1 = h0 * w2b.x + h1 * w2b.y + h2 * w2b.z + h3 * w2b.w;
#pragma unroll
    for (int off = 32; off > 0; off >>= 1) {
        a0 += __shfl_xor(a0, off);
        a1 += __shfl_xor(a1, off);
    }
    if (lane == 0) {
        out[p * 2 + 0] = ex + a0;
        out[p * 2 + 1] = ey + a1;
    }
}

extern "C" void kernel_launch(void* const* d_in, const int* in_sizes, int n_in,
                              void* d_out, int out_size, void* d_ws, size_t ws_size,
                              hipStream_t stream) {
    const float* feat = (const float*)d_in[0];
    const float* be   = (const float*)d_in[1];
    const float* W1   = (const float*)d_in[2];
    const float* b1   = (const float*)d_in[3];
    const float* W2   = (const float*)d_in[4];
    float* out = (float*)d_out;
    unsigned short* f2t = (unsigned short*)d_ws;   // 131072*256 bf16 = 64 MiB

    f2_gemm<<<4096, 256, 0, stream>>>(feat, W1, f2t);
    point_kernel<<<16384, 256, 0, stream>>>(f2t, be, b1, W2, out);
}